// Round 1
// baseline (50.300 us; speedup 1.0000x reference)
//
#include <hip/hip_runtime.h>
#include <math.h>

#define NN 384
#define DD 128
#define EPSF 1e-6f

// K1: M = G^T G   (M[a][b] = sum_c G[c][a]*G[c][b])  -- exactly symmetric
__global__ void k_gtg(const float* __restrict__ G, float* __restrict__ M) {
    int b = blockIdx.x * 16 + threadIdx.x;
    int a = blockIdx.y * 16 + threadIdx.y;
    float acc = 0.f;
    for (int c = 0; c < DD; ++c) acc = fmaf(G[c * DD + a], G[c * DD + b], acc);
    M[a * DD + b] = acc;
}

// K2: M2 = M^T M  (mirrors reference M.T @ M)
__global__ void k_mtm(const float* __restrict__ M, float* __restrict__ M2) {
    int b = blockIdx.x * 16 + threadIdx.x;
    int a = blockIdx.y * 16 + threadIdx.y;
    float acc = 0.f;
    for (int c = 0; c < DD; ++c) acc = fmaf(M[c * DD + a], M[c * DD + b], acc);
    M2[a * DD + b] = acc;
}

// K3: A = X*M, A2 = X*M2
__global__ void k_xm(const float* __restrict__ X, const float* __restrict__ M,
                     const float* __restrict__ M2,
                     float* __restrict__ A, float* __restrict__ A2) {
    int d = blockIdx.x * 16 + threadIdx.x;
    int i = blockIdx.y * 16 + threadIdx.y;
    float acc = 0.f, acc2 = 0.f;
    for (int c = 0; c < DD; ++c) {
        float x = X[i * DD + c];
        acc  = fmaf(x, M [c * DD + d], acc);
        acc2 = fmaf(x, M2[c * DD + d], acc2);
    }
    A [i * DD + d] = acc;
    A2[i * DD + d] = acc2;
}

// K4: prod[i] = dot(A[i], X[i]);  prod2[i] = dot(A2[i], X[i])
__global__ void k_prod(const float* __restrict__ X, const float* __restrict__ A,
                       const float* __restrict__ A2,
                       float* __restrict__ prod, float* __restrict__ prod2) {
    int i = blockIdx.x * blockDim.x + threadIdx.x;
    if (i >= NN) return;
    float p = 0.f, p2 = 0.f;
    for (int d = 0; d < DD; ++d) {
        float x = X[i * DD + d];
        p  = fmaf(A [i * DD + d], x, p);
        p2 = fmaf(A2[i * DD + d], x, p2);
    }
    prod [i] = p;
    prod2[i] = p2;
}

// K5: csmd[i][k] = prod[i]+prod[k]-2*dot(A[i],X[k])
//     invd[i][k] = 1/max(2*sqrt(max(csmd2,eps)),eps),  csmd2 from A2/prod2
__global__ void k_csmd(const float* __restrict__ X, const float* __restrict__ A,
                       const float* __restrict__ A2,
                       const float* __restrict__ prod, const float* __restrict__ prod2,
                       float* __restrict__ csmd, float* __restrict__ invd) {
    __shared__ float As[16][17], A2s[16][17], Xs[16][17];
    int tx = threadIdx.x, ty = threadIdx.y;
    int k = blockIdx.x * 16 + tx;
    int i = blockIdx.y * 16 + ty;
    float dA = 0.f, dA2 = 0.f;
    for (int d0 = 0; d0 < DD; d0 += 16) {
        As [ty][tx] = A [(blockIdx.y * 16 + ty) * DD + d0 + tx];
        A2s[ty][tx] = A2[(blockIdx.y * 16 + ty) * DD + d0 + tx];
        Xs [ty][tx] = X [(blockIdx.x * 16 + ty) * DD + d0 + tx];
        __syncthreads();
#pragma unroll
        for (int t = 0; t < 16; ++t) {
            float xv = Xs[tx][t];
            dA  = fmaf(As [ty][t], xv, dA);
            dA2 = fmaf(A2s[ty][t], xv, dA2);
        }
        __syncthreads();
    }
    float c1 = prod [i] + prod [k] - 2.f * dA;
    float c2 = prod2[i] + prod2[k] - 2.f * dA2;
    csmd[i * NN + k] = c1;
    float den = 2.f * sqrtf(fmaxf(c2, EPSF));
    den = fmaxf(den, EPSF);
    invd[i * NN + k] = 1.f / den;
}

// K6: the cube, compacted over valid j (y[j]==y[i], j!=i).
// out[i] = min_{k: y[k]!=y[i]} max(0, max_{valid j} relu(csmd[i,k]-csmd[i,j]) * invd[j,k])
__global__ void __launch_bounds__(NN) k_cube(const float* __restrict__ csmd,
                                             const float* __restrict__ invd,
                                             const int* __restrict__ y,
                                             float* __restrict__ out) {
    __shared__ float cvals[NN];
    __shared__ int   jidx[NN];
    __shared__ float red[NN];
    __shared__ int   cnt;
    int i = blockIdx.x;
    int t = threadIdx.x;
    int yi = y[i];
    if (t == 0) cnt = 0;
    __syncthreads();
    float cit = csmd[i * NN + t];   // csmd[i][t] : serves as c_ij (j=t) and c_ik (k=t)
    int yt = y[t];
    if (yt == yi && t != i) {
        int p = atomicAdd(&cnt, 1);
        cvals[p] = cit;
        jidx[p]  = t;
    }
    __syncthreads();
    int c = cnt;
    float m = 0.f;                  // zeroed margins contribute 0 to the max
    const float* invcol = invd + t; // invd[j*NN + t], coalesced across lanes
    for (int jj = 0; jj < c; ++jj) {
        float dlt = cit - cvals[jj];
        dlt = fmaxf(dlt, 0.f);
        float v = dlt * invcol[(size_t)jidx[jj] * NN];
        m = fmaxf(m, v);
    }
    if (yt == yi) m = __builtin_inff();   // exclude same-class k from the min
    red[t] = m;
    __syncthreads();
    if (t < 128) red[t] = fminf(red[t], fminf(red[t + 128], red[t + 256]));
    __syncthreads();
    if (t < 64) {
        float v = fminf(red[t], red[t + 64]);
        for (int off = 32; off > 0; off >>= 1)
            v = fminf(v, __shfl_down(v, off));
        if (t == 0) out[i] = v;
    }
}

extern "C" void kernel_launch(void* const* d_in, const int* in_sizes, int n_in,
                              void* d_out, int out_size, void* d_ws, size_t ws_size,
                              hipStream_t stream) {
    const float* X = (const float*)d_in[0];
    const float* G = (const float*)d_in[1];
    const int*   y = (const int*)d_in[2];

    float* ws    = (float*)d_ws;
    float* M     = ws;                 // 128*128
    float* M2    = M  + DD * DD;       // 128*128
    float* A     = M2 + DD * DD;       // 384*128
    float* A2    = A  + NN * DD;       // 384*128
    float* prod  = A2 + NN * DD;       // 384
    float* prod2 = prod + NN;          // 384
    float* csmd  = prod2 + NN;         // 384*384
    float* invd  = csmd + NN * NN;     // 384*384
    float* out   = (float*)d_out;

    dim3 b16(16, 16);
    k_gtg <<<dim3(DD / 16, DD / 16), b16, 0, stream>>>(G, M);
    k_mtm <<<dim3(DD / 16, DD / 16), b16, 0, stream>>>(M, M2);
    k_xm  <<<dim3(DD / 16, NN / 16), b16, 0, stream>>>(X, M, M2, A, A2);
    k_prod<<<dim3(3), dim3(128), 0, stream>>>(X, A, A2, prod, prod2);
    k_csmd<<<dim3(NN / 16, NN / 16), b16, 0, stream>>>(X, A, A2, prod, prod2, csmd, invd);
    k_cube<<<dim3(NN), dim3(NN), 0, stream>>>(csmd, invd, y, out);
}

// Round 2
// 39.420 us; speedup vs baseline: 1.2760x; 1.2760x over previous
//
#include <hip/hip_runtime.h>
#include <math.h>

#define NN 384
#define DD 128
#define EPSF 1e-6f
#define GP (DD + 4)   // padded LDS row stride (132 floats; 132*4B=528B, 16B-aligned)

// K_A: A = (X @ G^T) @ G   (== X @ (G^T G) since M symmetric)
//      prod[i] = dot(X_i, A_i),  p2[i] = dot(A_i, A_i)
// One block per 16 rows of X. G staged in LDS twice (row-major + transposed)
// so both GEMM passes do conflict-free ds_read_b128 along the K dim.
__global__ void __launch_bounds__(256) k_A(const float* __restrict__ X,
                                           const float* __restrict__ G,
                                           float* __restrict__ A,
                                           float* __restrict__ prod,
                                           float* __restrict__ p2) {
    __shared__ float Gs[DD][GP];    // G[c][d]
    __shared__ float GTs[DD][GP];   // G^T: GTs[d][c] = G[c][d]
    __shared__ float Xs[16][GP];
    __shared__ float Bs[16][GP];
    int tx = threadIdx.x, ty = threadIdx.y;
    int tid = ty * 16 + tx;
    int i0 = blockIdx.x * 16;

    // stage G row-major (float4) and transposed (scalar)
    for (int idx = tid; idx < DD * DD / 4; idx += 256) {
        int r = idx >> 5;                 // 32 float4 per row
        int c4 = (idx & 31) << 2;
        float4 g = ((const float4*)G)[idx];
        Gs[r][c4 + 0] = g.x; Gs[r][c4 + 1] = g.y;
        Gs[r][c4 + 2] = g.z; Gs[r][c4 + 3] = g.w;
        GTs[c4 + 0][r] = g.x; GTs[c4 + 1][r] = g.y;
        GTs[c4 + 2][r] = g.z; GTs[c4 + 3][r] = g.w;
    }
    // stage X tile
    for (int idx = tid; idx < 16 * DD / 4; idx += 256) {
        int r = idx >> 5;
        int c4 = (idx & 31) << 2;
        float4 x = ((const float4*)(X + (size_t)i0 * DD))[idx];
        Xs[r][c4 + 0] = x.x; Xs[r][c4 + 1] = x.y;
        Xs[r][c4 + 2] = x.z; Xs[r][c4 + 3] = x.w;
    }
    __syncthreads();

    // pass 1: B[ty][c] = sum_d Xs[ty][d] * G[c][d],  c = tx + 16e
    float bacc[8] = {0.f, 0.f, 0.f, 0.f, 0.f, 0.f, 0.f, 0.f};
    for (int d4 = 0; d4 < DD; d4 += 4) {
        float4 xv = *(const float4*)&Xs[ty][d4];
#pragma unroll
        for (int e = 0; e < 8; ++e) {
            const float4 gv = *(const float4*)&Gs[tx + 16 * e][d4];
            bacc[e] = fmaf(xv.x, gv.x, bacc[e]);
            bacc[e] = fmaf(xv.y, gv.y, bacc[e]);
            bacc[e] = fmaf(xv.z, gv.z, bacc[e]);
            bacc[e] = fmaf(xv.w, gv.w, bacc[e]);
        }
    }
#pragma unroll
    for (int e = 0; e < 8; ++e) Bs[ty][tx + 16 * e] = bacc[e];
    __syncthreads();

    // pass 2: A[ty][dc] = sum_c B[ty][c] * G[c][dc],  dc = tx + 16e
    float aacc[8] = {0.f, 0.f, 0.f, 0.f, 0.f, 0.f, 0.f, 0.f};
    for (int c4 = 0; c4 < DD; c4 += 4) {
        float4 bv = *(const float4*)&Bs[ty][c4];
#pragma unroll
        for (int e = 0; e < 8; ++e) {
            const float4 gv = *(const float4*)&GTs[tx + 16 * e][c4];  // G[c][dc] over c
            aacc[e] = fmaf(bv.x, gv.x, aacc[e]);
            aacc[e] = fmaf(bv.y, gv.y, aacc[e]);
            aacc[e] = fmaf(bv.z, gv.z, aacc[e]);
            aacc[e] = fmaf(bv.w, gv.w, aacc[e]);
        }
    }
    // write A + row dots
    float pp = 0.f, qq = 0.f;
#pragma unroll
    for (int e = 0; e < 8; ++e) {
        int dc = tx + 16 * e;
        A[(size_t)(i0 + ty) * DD + dc] = aacc[e];
        pp = fmaf(aacc[e], Xs[ty][dc], pp);
        qq = fmaf(aacc[e], aacc[e], qq);
    }
#pragma unroll
    for (int off = 1; off < 16; off <<= 1) {
        pp += __shfl_xor(pp, off);
        qq += __shfl_xor(qq, off);
    }
    if (tx == 0) { prod[i0 + ty] = pp; p2[i0 + ty] = qq; }
}

// K_csmd: csmd[i][k] = prod[i]+prod[k]-2*dot(A_i,X_k)
//         invd[i][k] = 1/max(2*sqrt(max(p2[i]+p2[k]-2*dot(A_i,A_k), eps)), eps)
__global__ void __launch_bounds__(256) k_csmd(const float* __restrict__ X,
                                              const float* __restrict__ A,
                                              const float* __restrict__ prod,
                                              const float* __restrict__ p2,
                                              float* __restrict__ csmd,
                                              float* __restrict__ invd) {
    __shared__ float Ai[16][20], Xk[16][20], Ak[16][20];
    int tx = threadIdx.x, ty = threadIdx.y;
    int k0 = blockIdx.x * 16, i0 = blockIdx.y * 16;
    float dA = 0.f, dAA = 0.f;
    for (int d0 = 0; d0 < DD; d0 += 16) {
        Ai[ty][tx] = A[(size_t)(i0 + ty) * DD + d0 + tx];
        Xk[ty][tx] = X[(size_t)(k0 + ty) * DD + d0 + tx];
        Ak[ty][tx] = A[(size_t)(k0 + ty) * DD + d0 + tx];
        __syncthreads();
#pragma unroll
        for (int t4 = 0; t4 < 16; t4 += 4) {
            float4 a  = *(const float4*)&Ai[ty][t4];
            float4 x  = *(const float4*)&Xk[tx][t4];
            float4 ak = *(const float4*)&Ak[tx][t4];
            dA  = fmaf(a.x, x.x,  dA);  dA  = fmaf(a.y, x.y,  dA);
            dA  = fmaf(a.z, x.z,  dA);  dA  = fmaf(a.w, x.w,  dA);
            dAA = fmaf(a.x, ak.x, dAA); dAA = fmaf(a.y, ak.y, dAA);
            dAA = fmaf(a.z, ak.z, dAA); dAA = fmaf(a.w, ak.w, dAA);
        }
        __syncthreads();
    }
    int i = i0 + ty, k = k0 + tx;
    float c1 = prod[i] + prod[k] - 2.f * dA;
    csmd[(size_t)i * NN + k] = c1;
    float c2 = p2[i] + p2[k] - 2.f * dAA;
    float den = fmaxf(2.f * sqrtf(fmaxf(c2, EPSF)), EPSF);
    invd[(size_t)i * NN + k] = 1.f / den;
}

// K_cube: out[i] = min_{k: y[k]!=y[i]} max_{j: y[j]==y[i], j!=i} relu(csmd[i,k]-csmd[i,j]) * invd[j,k]
__global__ void __launch_bounds__(NN) k_cube(const float* __restrict__ csmd,
                                             const float* __restrict__ invd,
                                             const int* __restrict__ y,
                                             float* __restrict__ out) {
    __shared__ float cvals[NN];
    __shared__ int   jidx[NN];
    __shared__ float red[NN];
    __shared__ int   cnt;
    int i = blockIdx.x;
    int t = threadIdx.x;
    int yi = y[i];
    if (t == 0) cnt = 0;
    __syncthreads();
    float cit = csmd[(size_t)i * NN + t];
    int yt = y[t];
    if (yt == yi && t != i) {
        int p = atomicAdd(&cnt, 1);
        cvals[p] = cit;
        jidx[p]  = t;
    }
    __syncthreads();
    int c = cnt;
    float m = 0.f;
    const float* invcol = invd + t;
    for (int jj = 0; jj < c; ++jj) {
        float dlt = fmaxf(cit - cvals[jj], 0.f);
        float v = dlt * invcol[(size_t)jidx[jj] * NN];
        m = fmaxf(m, v);
    }
    if (yt == yi) m = __builtin_inff();
    red[t] = m;
    __syncthreads();
    if (t < 128) red[t] = fminf(red[t], fminf(red[t + 128], red[t + 256]));
    __syncthreads();
    if (t < 64) {
        float v = fminf(red[t], red[t + 64]);
        for (int off = 32; off > 0; off >>= 1)
            v = fminf(v, __shfl_down(v, off));
        if (t == 0) out[i] = v;
    }
}

extern "C" void kernel_launch(void* const* d_in, const int* in_sizes, int n_in,
                              void* d_out, int out_size, void* d_ws, size_t ws_size,
                              hipStream_t stream) {
    const float* X = (const float*)d_in[0];
    const float* G = (const float*)d_in[1];
    const int*   y = (const int*)d_in[2];

    float* ws   = (float*)d_ws;
    float* A    = ws;                  // 384*128
    float* prod = A + NN * DD;         // 384
    float* p2   = prod + NN;           // 384
    float* csmd = p2 + NN;             // 384*384
    float* invd = csmd + NN * NN;      // 384*384
    float* out  = (float*)d_out;

    k_A   <<<dim3(NN / 16), dim3(16, 16), 0, stream>>>(X, G, A, prod, p2);
    k_csmd<<<dim3(NN / 16, NN / 16), dim3(16, 16), 0, stream>>>(X, A, prod, p2, csmd, invd);
    k_cube<<<dim3(NN), dim3(NN), 0, stream>>>(csmd, invd, y, out);
}